// Round 13
// baseline (1525.452 us; speedup 1.0000x reference)
//
#include <hip/hip_runtime.h>
#include <hip/hip_bf16.h>

#define NE 8
#define HD 256
#define NTHREADS 256

typedef __attribute__((ext_vector_type(8))) short short8;
typedef __attribute__((ext_vector_type(4))) float f32x4;

__device__ __forceinline__ unsigned short f2bf_u16(float f) {
    union { __hip_bfloat16 b; unsigned short u; } v;
    v.b = __float2bfloat16(f);          // HW RNE convert
    return v.u;
}
__device__ __forceinline__ unsigned int pack2bf(float lo, float hi) {
    return (unsigned int)f2bf_u16(lo) | ((unsigned int)f2bf_u16(hi) << 16);
}

// One-time prep: W[e][k][n] fp32 -> Wt[e][n][k] bf16 (contiguous-K A-fragments).
__global__ void prep_weights(const float* __restrict__ W1, const float* __restrict__ W2,
                             unsigned short* __restrict__ W1t, unsigned short* __restrict__ W2t) {
    int idx = blockIdx.x * blockDim.x + threadIdx.x;
    if (idx >= NE * HD * HD) return;
    int nn = idx & 255;          // coalesced read dim
    int kk = (idx >> 8) & 255;
    int e  = idx >> 16;
    W1t[(e * HD + nn) * HD + kk] = f2bf_u16(W1[(e * HD + kk) * HD + nn]);
    W2t[(e * HD + nn) * HD + kk] = f2bf_u16(W2[(e * HD + kk) * HD + nn]);
}

// Barrier-free fused MLP: each wave owns 16 points (point = l15) and computes
// the full 4-layer network for one expert. Inter-layer transpose via a
// wave-PRIVATE LDS slice (same-wave ds ordering, no __syncthreads).
// blockIdx = e*ntiles + tile (expert-major for L1 weight reuse on a CU).
__global__ __launch_bounds__(NTHREADS, 2) void moe_mlp(
    const float* __restrict__ coords, int npts,
    const float* __restrict__ W0, const float* __restrict__ b0,
    const unsigned short* __restrict__ W1t, const float* __restrict__ b1,
    const unsigned short* __restrict__ W2t, const float* __restrict__ b2,
    const float* __restrict__ W3, const float* __restrict__ b3,
    float* __restrict__ ws)
{
    __shared__ __align__(16) unsigned short ActS[4 * 16 * HD];   // 4 waves x 8 KB

    const int t = threadIdx.x;
    const int lane = t & 63;
    const int w = t >> 6;
    const int l15 = lane & 15;
    const int kg = lane >> 4;

    const int ntiles = (npts + 63) >> 6;         // 64 points per block
    const int e = blockIdx.x / ntiles;
    const int tile = blockIdx.x - e * ntiles;
    const int p0 = tile * 64 + w * 16;
    if (p0 >= npts) return;                      // wave-uniform tail exit
    const int p = p0 + l15;
    const int pc = p < npts ? p : npts - 1;      // clamp; store masked later

    const float x = coords[pc * 3];
    const float y = coords[pc * 3 + 1];
    const float z = coords[pc * 3 + 2];

    unsigned short* Aw = ActS + w * (16 * HD);   // wave-private slice
    const int swx = (l15 & 7) << 3;              // row-XOR (bank swizzle)

    // ---- L0 (3 -> 256), output directly as L1 B-fragments in registers:
    //      b1f[ks] = bf16 x8, k = ks*32 + kg*8 + j, point = l15. ----
    short8 b1f[8];
    {
        const float* W0e = W0 + e * 3 * HD;
        const float* b0e = b0 + e * HD;
        #pragma unroll
        for (int ks = 0; ks < 8; ++ks) {
            const int n0 = ks * 32 + kg * 8;
            f32x4 wx0 = *(const f32x4*)(W0e + n0);
            f32x4 wx1 = *(const f32x4*)(W0e + n0 + 4);
            f32x4 wy0 = *(const f32x4*)(W0e + HD + n0);
            f32x4 wy1 = *(const f32x4*)(W0e + HD + n0 + 4);
            f32x4 wz0 = *(const f32x4*)(W0e + 2 * HD + n0);
            f32x4 wz1 = *(const f32x4*)(W0e + 2 * HD + n0 + 4);
            f32x4 bv0 = *(const f32x4*)(b0e + n0);
            f32x4 bv1 = *(const f32x4*)(b0e + n0 + 4);
            union { unsigned int u[4]; short8 s; } cv;
            float h0 = fmaxf(x*wx0[0] + y*wy0[0] + z*wz0[0] + bv0[0], 0.f);
            float h1 = fmaxf(x*wx0[1] + y*wy0[1] + z*wz0[1] + bv0[1], 0.f);
            float h2 = fmaxf(x*wx0[2] + y*wy0[2] + z*wz0[2] + bv0[2], 0.f);
            float h3 = fmaxf(x*wx0[3] + y*wy0[3] + z*wz0[3] + bv0[3], 0.f);
            cv.u[0] = pack2bf(h0, h1); cv.u[1] = pack2bf(h2, h3);
            h0 = fmaxf(x*wx1[0] + y*wy1[0] + z*wz1[0] + bv1[0], 0.f);
            h1 = fmaxf(x*wx1[1] + y*wy1[1] + z*wz1[1] + bv1[1], 0.f);
            h2 = fmaxf(x*wx1[2] + y*wy1[2] + z*wz1[2] + bv1[2], 0.f);
            h3 = fmaxf(x*wx1[3] + y*wy1[3] + z*wz1[3] + bv1[3], 0.f);
            cv.u[2] = pack2bf(h0, h1); cv.u[3] = pack2bf(h2, h3);
            b1f[ks] = cv.s;
        }
    }

    // ---- L1 (256 -> 256): acc[mt] covers neurons mt*16 + (kg*4+r), point l15 ----
    f32x4 acc[16];
    #pragma unroll
    for (int mt = 0; mt < 16; ++mt) acc[mt] = (f32x4){0.f, 0.f, 0.f, 0.f};
    {
        const unsigned short* W1e = W1t + e * HD * HD + l15 * HD;
        #pragma unroll
        for (int ks = 0; ks < 8; ++ks) {
            const int k0 = ks * 32 + kg * 8;
            #pragma unroll
            for (int mt = 0; mt < 16; ++mt) {
                short8 af = *(const short8*)(W1e + mt * 16 * HD + k0);
                acc[mt] = __builtin_amdgcn_mfma_f32_16x16x32_bf16(af, b1f[ks], acc[mt], 0, 0, 0);
            }
        }
    }
    // epilogue: bias+relu -> wave-private LDS (row = l15, col = neuron, XOR swizzle)
    {
        const float* b1e = b1 + e * HD;
        #pragma unroll
        for (int mt = 0; mt < 16; ++mt) {
            const int n0 = mt * 16 + kg * 4;
            f32x4 bb = *(const f32x4*)(b1e + n0);
            uint2 pkt;
            pkt.x = pack2bf(fmaxf(acc[mt][0] + bb[0], 0.f), fmaxf(acc[mt][1] + bb[1], 0.f));
            pkt.y = pack2bf(fmaxf(acc[mt][2] + bb[2], 0.f), fmaxf(acc[mt][3] + bb[3], 0.f));
            *(uint2*)(Aw + l15 * HD + (n0 ^ swx)) = pkt;
        }
    }

    // ---- L2 (256 -> 256): B-frags re-read from private LDS (8 ds_read_b128) ----
    #pragma unroll
    for (int mt = 0; mt < 16; ++mt) acc[mt] = (f32x4){0.f, 0.f, 0.f, 0.f};
    {
        const unsigned short* W2e = W2t + e * HD * HD + l15 * HD;
        #pragma unroll
        for (int ks = 0; ks < 8; ++ks) {
            const int k0 = ks * 32 + kg * 8;
            short8 bf = *(const short8*)(Aw + l15 * HD + (k0 ^ swx));
            #pragma unroll
            for (int mt = 0; mt < 16; ++mt) {
                short8 af = *(const short8*)(W2e + mt * 16 * HD + k0);
                acc[mt] = __builtin_amdgcn_mfma_f32_16x16x32_bf16(af, bf, acc[mt], 0, 0, 0);
            }
        }
    }

    // ---- L3 (256 -> 1), fused in registers; reduce over kg ----
    {
        const float* b2e = b2 + e * HD;
        const float* W3e = W3 + e * HD;
        float s = 0.f;
        #pragma unroll
        for (int mt = 0; mt < 16; ++mt) {
            const int n0 = mt * 16 + kg * 4;
            f32x4 bb = *(const f32x4*)(b2e + n0);
            f32x4 w3 = *(const f32x4*)(W3e + n0);
            #pragma unroll
            for (int r = 0; r < 4; ++r)
                s += fmaxf(acc[mt][r] + bb[r], 0.f) * w3[r];
        }
        s += __shfl_xor(s, 16);
        s += __shfl_xor(s, 32);
        if (kg == 0 && p < npts) ws[e * npts + p] = s + b3[e];
    }
}

// Max over the 8 experts' partials.
__global__ void moe_reduce(const float* __restrict__ ws, float* __restrict__ out, int npts) {
    int p = blockIdx.x * 256 + threadIdx.x;
    if (p >= npts) return;
    float m = ws[p];
    #pragma unroll
    for (int e = 1; e < NE; ++e) m = fmaxf(m, ws[e * npts + p]);
    out[p] = m;
}

extern "C" void kernel_launch(void* const* d_in, const int* in_sizes, int n_in,
                              void* d_out, int out_size, void* d_ws, size_t ws_size,
                              hipStream_t stream) {
    const float* coords = (const float*)d_in[0];
    const float* W0 = (const float*)d_in[1];
    const float* b0 = (const float*)d_in[2];
    const float* W1 = (const float*)d_in[3];
    const float* b1 = (const float*)d_in[4];
    const float* W2 = (const float*)d_in[5];
    const float* b2 = (const float*)d_in[6];
    const float* W3 = (const float*)d_in[7];
    const float* b3 = (const float*)d_in[8];
    const int npts = in_sizes[0] / 3;

    unsigned short* W1t = (unsigned short*)d_ws;               // 1 MB
    unsigned short* W2t = W1t + NE * HD * HD;                  // 1 MB
    float* eout = (float*)(W2t + NE * HD * HD);                // 8*npts floats

    prep_weights<<<(NE * HD * HD + 255) / 256, 256, 0, stream>>>(W1, W2, W1t, W2t);

    const int ntiles = (npts + 63) / 64;
    moe_mlp<<<ntiles * NE, NTHREADS, 0, stream>>>(
        coords, npts, W0, b0, W1t, b1, W2t, b2, W3, b3, eout);

    moe_reduce<<<(npts + 255) / 256, 256, 0, stream>>>(eout, (float*)d_out, npts);
}

// Round 14
// 411.149 us; speedup vs baseline: 3.7102x; 3.7102x over previous
//
#include <hip/hip_runtime.h>
#include <hip/hip_bf16.h>

#define NE 8
#define HD 256
#define NT 64
#define NTHREADS 256

typedef __attribute__((ext_vector_type(8))) short short8;
typedef __attribute__((ext_vector_type(4))) float f32x4;

__device__ __forceinline__ unsigned short f2bf_u16(float f) {
    union { __hip_bfloat16 b; unsigned short u; } v;
    v.b = __float2bfloat16(f);          // HW RNE convert
    return v.u;
}
__device__ __forceinline__ unsigned int pack2bf(float lo, float hi) {
    return (unsigned int)f2bf_u16(lo) | ((unsigned int)f2bf_u16(hi) << 16);
}
// XOR-swizzled LDS index (element units); keeps 16B chunks aligned and 8B
// groups intact (XOR operand is a multiple of 8 elements).
__device__ __forceinline__ int swz(int row, int col) {
    return row * HD + (col ^ ((row & 7) << 3));
}

// One-time prep: W[e][k][n] fp32 -> Wt[e][n][k] bf16 (contiguous-K A-fragments).
__global__ void prep_weights(const float* __restrict__ W1, const float* __restrict__ W2,
                             unsigned short* __restrict__ W1t, unsigned short* __restrict__ W2t) {
    int idx = blockIdx.x * blockDim.x + threadIdx.x;
    if (idx >= NE * HD * HD) return;
    int nn = idx & 255;          // coalesced read dim
    int kk = (idx >> 8) & 255;
    int e  = idx >> 16;
    W1t[(e * HD + nn) * HD + kk] = f2bf_u16(W1[(e * HD + kk) * HD + nn]);
    W2t[(e * HD + nn) * HD + kk] = f2bf_u16(W2[(e * HD + kk) * HD + nn]);
}

// K-loop: wave w owns neurons [w*64, w*64+64) (mt=4), iterates all 64 points
// (nt=4). 1-deep software pipeline: ks+1's 4 af (global) + 4 bf (LDS) loads
// issue while ks's 16 MFMAs run. ~140 live VGPRs — needs the (,2) bound.
__device__ __forceinline__ void gemm_kloop(
    const unsigned short* Act, const unsigned short* __restrict__ Wt,
    int w, int l15, int kg, f32x4 acc[4][4])
{
    #pragma unroll
    for (int mt = 0; mt < 4; ++mt)
        #pragma unroll
        for (int nt = 0; nt < 4; ++nt)
            acc[mt][nt] = (f32x4){0.f, 0.f, 0.f, 0.f};

    const unsigned short* Wr = Wt + (w * 64 + l15) * HD;

    int k0 = kg * 8;
    short8 af0 = *(const short8*)(Wr + 0 * 16 * HD + k0);
    short8 af1 = *(const short8*)(Wr + 1 * 16 * HD + k0);
    short8 af2 = *(const short8*)(Wr + 2 * 16 * HD + k0);
    short8 af3 = *(const short8*)(Wr + 3 * 16 * HD + k0);
    short8 bf0 = *(const short8*)(Act + swz(0 * 16 + l15, k0));
    short8 bf1 = *(const short8*)(Act + swz(1 * 16 + l15, k0));
    short8 bf2 = *(const short8*)(Act + swz(2 * 16 + l15, k0));
    short8 bf3 = *(const short8*)(Act + swz(3 * 16 + l15, k0));

    #pragma unroll
    for (int ks = 0; ks < 8; ++ks) {
        short8 naf0, naf1, naf2, naf3, nbf0, nbf1, nbf2, nbf3;
        if (ks < 7) {
            const int k1 = (ks + 1) * 32 + kg * 8;
            naf0 = *(const short8*)(Wr + 0 * 16 * HD + k1);
            naf1 = *(const short8*)(Wr + 1 * 16 * HD + k1);
            naf2 = *(const short8*)(Wr + 2 * 16 * HD + k1);
            naf3 = *(const short8*)(Wr + 3 * 16 * HD + k1);
            nbf0 = *(const short8*)(Act + swz(0 * 16 + l15, k1));
            nbf1 = *(const short8*)(Act + swz(1 * 16 + l15, k1));
            nbf2 = *(const short8*)(Act + swz(2 * 16 + l15, k1));
            nbf3 = *(const short8*)(Act + swz(3 * 16 + l15, k1));
        }
        acc[0][0] = __builtin_amdgcn_mfma_f32_16x16x32_bf16(af0, bf0, acc[0][0], 0, 0, 0);
        acc[0][1] = __builtin_amdgcn_mfma_f32_16x16x32_bf16(af0, bf1, acc[0][1], 0, 0, 0);
        acc[0][2] = __builtin_amdgcn_mfma_f32_16x16x32_bf16(af0, bf2, acc[0][2], 0, 0, 0);
        acc[0][3] = __builtin_amdgcn_mfma_f32_16x16x32_bf16(af0, bf3, acc[0][3], 0, 0, 0);
        acc[1][0] = __builtin_amdgcn_mfma_f32_16x16x32_bf16(af1, bf0, acc[1][0], 0, 0, 0);
        acc[1][1] = __builtin_amdgcn_mfma_f32_16x16x32_bf16(af1, bf1, acc[1][1], 0, 0, 0);
        acc[1][2] = __builtin_amdgcn_mfma_f32_16x16x32_bf16(af1, bf2, acc[1][2], 0, 0, 0);
        acc[1][3] = __builtin_amdgcn_mfma_f32_16x16x32_bf16(af1, bf3, acc[1][3], 0, 0, 0);
        acc[2][0] = __builtin_amdgcn_mfma_f32_16x16x32_bf16(af2, bf0, acc[2][0], 0, 0, 0);
        acc[2][1] = __builtin_amdgcn_mfma_f32_16x16x32_bf16(af2, bf1, acc[2][1], 0, 0, 0);
        acc[2][2] = __builtin_amdgcn_mfma_f32_16x16x32_bf16(af2, bf2, acc[2][2], 0, 0, 0);
        acc[2][3] = __builtin_amdgcn_mfma_f32_16x16x32_bf16(af2, bf3, acc[2][3], 0, 0, 0);
        acc[3][0] = __builtin_amdgcn_mfma_f32_16x16x32_bf16(af3, bf0, acc[3][0], 0, 0, 0);
        acc[3][1] = __builtin_amdgcn_mfma_f32_16x16x32_bf16(af3, bf1, acc[3][1], 0, 0, 0);
        acc[3][2] = __builtin_amdgcn_mfma_f32_16x16x32_bf16(af3, bf2, acc[3][2], 0, 0, 0);
        acc[3][3] = __builtin_amdgcn_mfma_f32_16x16x32_bf16(af3, bf3, acc[3][3], 0, 0, 0);
        af0 = naf0; af1 = naf1; af2 = naf2; af3 = naf3;
        bf0 = nbf0; bf1 = nbf1; bf2 = nbf2; bf3 = nbf3;
    }
}

// One expert per block: blockIdx = tile*8 + e. 4 waves, 5 barrier phases.
__global__ __launch_bounds__(NTHREADS, 2) void moe_expert(
    const float* __restrict__ coords, int npts,
    const float* __restrict__ W0, const float* __restrict__ b0,
    const unsigned short* __restrict__ W1t, const float* __restrict__ b1,
    const unsigned short* __restrict__ W2t, const float* __restrict__ b2,
    const float* __restrict__ W3, const float* __restrict__ b3,
    float* __restrict__ ws)
{
    __shared__ __align__(16) unsigned short Act[NT * HD];   // 32 KB
    __shared__ float cbuf[NT * 3];                          // 768 B
    __shared__ float pscr[NT * 4];                          // 1 KB

    const int t = threadIdx.x;
    const int lane = t & 63;
    const int w = t >> 6;       // 0..3: neuron group of 64
    const int l15 = lane & 15;
    const int kg = lane >> 4;
    const int e = blockIdx.x & 7;
    const int p0 = (blockIdx.x >> 3) * NT;

    if (t < NT * 3) {
        int idx = p0 * 3 + t;
        int lim = npts * 3 - 1;
        cbuf[t] = coords[idx < lim ? idx : lim];   // clamp: in-bounds, tail masked on store
    }
    __syncthreads();

    // ---- layer 0: 3 -> 256, fp32 VALU, packed b32 writes ----
    {
        const int j2 = (t & 127) * 2;            // 2 consecutive neurons
        const int prow0 = (t >> 7) * 32;         // 32 points per half
        const float wx0 = W0[(e*3+0)*HD + j2], wx1 = W0[(e*3+0)*HD + j2+1];
        const float wy0 = W0[(e*3+1)*HD + j2], wy1 = W0[(e*3+1)*HD + j2+1];
        const float wz0 = W0[(e*3+2)*HD + j2], wz1 = W0[(e*3+2)*HD + j2+1];
        const float bb0 = b0[e*HD + j2],       bb1 = b0[e*HD + j2+1];
        #pragma unroll 4
        for (int pp = 0; pp < 32; ++pp) {
            int p = prow0 + pp;
            float x = cbuf[p*3], y = cbuf[p*3+1], z = cbuf[p*3+2];
            float h0 = fmaxf(x*wx0 + y*wy0 + z*wz0 + bb0, 0.f);
            float h1 = fmaxf(x*wx1 + y*wy1 + z*wz1 + bb1, 0.f);
            *(unsigned int*)(Act + swz(p, j2)) = pack2bf(h0, h1);
        }
    }
    __syncthreads();

    f32x4 acc[4][4];
    // ---- layer 1 K-loop ----
    gemm_kloop(Act, W1t + e*HD*HD, w, l15, kg, acc);
    __syncthreads();   // all reads done -> overwrite Act in place
    // ---- layer 1 epilogue: bias+relu, packed 8B writes ----
    #pragma unroll
    for (int mt = 0; mt < 4; ++mt) {
        const int n0 = w * 64 + mt * 16 + kg * 4;
        const f32x4 bb = *(const f32x4*)(b1 + e*HD + n0);
        #pragma unroll
        for (int nt = 0; nt < 4; ++nt) {
            const int p = nt * 16 + l15;
            unsigned int lo = pack2bf(fmaxf(acc[mt][nt][0] + bb[0], 0.f),
                                      fmaxf(acc[mt][nt][1] + bb[1], 0.f));
            unsigned int hi = pack2bf(fmaxf(acc[mt][nt][2] + bb[2], 0.f),
                                      fmaxf(acc[mt][nt][3] + bb[3], 0.f));
            *(uint2*)(Act + swz(p, n0)) = make_uint2(lo, hi);
        }
    }
    __syncthreads();
    // ---- layer 2 K-loop ----
    gemm_kloop(Act, W2t + e*HD*HD, w, l15, kg, acc);
    // ---- fused layer-2 epilogue + layer 3 (fp32, in registers) ----
    #pragma unroll
    for (int nt = 0; nt < 4; ++nt) {
        float s = 0.f;
        #pragma unroll
        for (int mt = 0; mt < 4; ++mt) {
            const int nb = w * 64 + mt * 16 + kg * 4;
            const f32x4 bb = *(const f32x4*)(b2 + e*HD + nb);
            const f32x4 w3 = *(const f32x4*)(W3 + e*HD + nb);
            #pragma unroll
            for (int r = 0; r < 4; ++r)
                s += fmaxf(acc[mt][nt][r] + bb[r], 0.f) * w3[r];
        }
        s += __shfl_xor(s, 16);   // reduce over kg (4 lanes per point)
        s += __shfl_xor(s, 32);
        if (kg == 0) pscr[(nt * 16 + l15) * 4 + w] = s;  // per-wave partial
    }
    __syncthreads();
    if (t < NT) {
        f32x4 v = *(const f32x4*)(pscr + t * 4);
        int p = p0 + t;
        if (p < npts) ws[e * npts + p] = v[0] + v[1] + v[2] + v[3] + b3[e];
    }
}

// Max over the 8 experts' partials.
__global__ void moe_reduce(const float* __restrict__ ws, float* __restrict__ out, int npts) {
    int p = blockIdx.x * 256 + threadIdx.x;
    if (p >= npts) return;
    float m = ws[p];
    #pragma unroll
    for (int e = 1; e < NE; ++e) m = fmaxf(m, ws[e * npts + p]);
    out[p] = m;
}

extern "C" void kernel_launch(void* const* d_in, const int* in_sizes, int n_in,
                              void* d_out, int out_size, void* d_ws, size_t ws_size,
                              hipStream_t stream) {
    const float* coords = (const float*)d_in[0];
    const float* W0 = (const float*)d_in[1];
    const float* b0 = (const float*)d_in[2];
    const float* W1 = (const float*)d_in[3];
    const float* b1 = (const float*)d_in[4];
    const float* W2 = (const float*)d_in[5];
    const float* b2 = (const float*)d_in[6];
    const float* W3 = (const float*)d_in[7];
    const float* b3 = (const float*)d_in[8];
    const int npts = in_sizes[0] / 3;

    unsigned short* W1t = (unsigned short*)d_ws;               // 1 MB
    unsigned short* W2t = W1t + NE * HD * HD;                  // 1 MB
    float* eout = (float*)(W2t + NE * HD * HD);                // 8*npts floats

    prep_weights<<<(NE * HD * HD + 255) / 256, 256, 0, stream>>>(W1, W2, W1t, W2t);

    int ntiles = (npts + NT - 1) / NT;
    moe_expert<<<ntiles * NE, NTHREADS, 0, stream>>>(
        coords, npts, W0, b0, W1t, b1, W2t, b2, W3, b3, eout);

    moe_reduce<<<(npts + 255) / 256, 256, 0, stream>>>(eout, (float*)d_out, npts);
}

// Round 17
// 309.228 us; speedup vs baseline: 4.9331x; 1.3296x over previous
//
#include <hip/hip_runtime.h>
#include <hip/hip_bf16.h>

#define NE 8
#define HD 256
#define NT 64
#define NTHREADS 256
#define WPITCH 40                      // 32 k + 8 pad elems; 80 B rows (16B-aligned)
#define SLICE_ELEMS (HD * WPITCH)      // 10240 elems = 20480 B per K-slice

typedef __attribute__((ext_vector_type(8))) short short8;
typedef __attribute__((ext_vector_type(4))) float f32x4;

__device__ __forceinline__ unsigned short f2bf_u16(float f) {
    union { __hip_bfloat16 b; unsigned short u; } v;
    v.b = __float2bfloat16(f);          // HW RNE convert
    return v.u;
}
__device__ __forceinline__ unsigned int pack2bf(float lo, float hi) {
    return (unsigned int)f2bf_u16(lo) | ((unsigned int)f2bf_u16(hi) << 16);
}
// Act LDS swizzle (element units), proven in R12.
__device__ __forceinline__ int swz(int row, int col) {
    return row * HD + (col ^ ((row & 7) << 3));
}

// Weights pre-swizzled: Wp[e][slice s][n][WPITCH], [n][0..31] = W[k=s*32+kk][n].
// Linear global_load_lds staging reproduces this layout in LDS verbatim.
__global__ void prep_weights(const float* __restrict__ W1, const float* __restrict__ W2,
                             unsigned short* __restrict__ W1p, unsigned short* __restrict__ W2p) {
    int idx = blockIdx.x * blockDim.x + threadIdx.x;
    const int TOT = NE * 8 * SLICE_ELEMS;
    if (idx >= TOT) return;
    int kk = idx % WPITCH;
    int n  = (idx / WPITCH) % HD;
    int s  = (idx / (WPITCH * HD)) % 8;
    int e  = idx / (WPITCH * HD * 8);
    float v1 = 0.f, v2 = 0.f;
    if (kk < 32) {
        int k = s * 32 + kk;
        v1 = W1[(e * HD + k) * HD + n];
        v2 = W2[(e * HD + k) * HD + n];
    }
    W1p[idx] = f2bf_u16(v1);
    W2p[idx] = f2bf_u16(v2);
}

// Async stage one K-slice QUARTER: wave w covers bytes [w*5120, w*5120+5120)
// = weight rows [w*64, w*64+64) — exactly the rows wave w later reads.
// Completion is guaranteed by the per-slice __syncthreads (full vmcnt drain).
__device__ __forceinline__ void stage_slice(const unsigned short* __restrict__ gsrc,
                                            unsigned short* lbase, int w, int lane) {
    const char* g = (const char*)gsrc + w * 5120 + lane * 16;
    char* l = (char*)lbase + w * 5120;
    #pragma unroll
    for (int i = 0; i < 5; ++i)
        __builtin_amdgcn_global_load_lds(
            (const __attribute__((address_space(1))) unsigned int*)(g + i * 1024),
            (__attribute__((address_space(3))) unsigned int*)(l + i * 1024),
            16, 0, 0);
}

#define KSLICE_BODY(CURBUF)                                                              \
    {                                                                                    \
        const unsigned short* Ar = (CURBUF) + (w*64 + l15) * WPITCH + kg*8;              \
        short8 af0 = *(const short8*)(Ar + 0*16*WPITCH);                                 \
        short8 af1 = *(const short8*)(Ar + 1*16*WPITCH);                                 \
        short8 af2 = *(const short8*)(Ar + 2*16*WPITCH);                                 \
        short8 af3 = *(const short8*)(Ar + 3*16*WPITCH);                                 \
        const int k0 = s*32 + kg*8;                                                      \
        short8 bf0 = *(const short8*)(Act + swz(0*16 + l15, k0));                        \
        short8 bf1 = *(const short8*)(Act + swz(1*16 + l15, k0));                        \
        short8 bf2 = *(const short8*)(Act + swz(2*16 + l15, k0));                        \
        short8 bf3 = *(const short8*)(Act + swz(3*16 + l15, k0));                        \
        acc[0][0] = __builtin_amdgcn_mfma_f32_16x16x32_bf16(af0, bf0, acc[0][0], 0,0,0); \
        acc[0][1] = __builtin_amdgcn_mfma_f32_16x16x32_bf16(af0, bf1, acc[0][1], 0,0,0); \
        acc[0][2] = __builtin_amdgcn_mfma_f32_16x16x32_bf16(af0, bf2, acc[0][2], 0,0,0); \
        acc[0][3] = __builtin_amdgcn_mfma_f32_16x16x32_bf16(af0, bf3, acc[0][3], 0,0,0); \
        acc[1][0] = __builtin_amdgcn_mfma_f32_16x16x32_bf16(af1, bf0, acc[1][0], 0,0,0); \
        acc[1][1] = __builtin_amdgcn_mfma_f32_16x16x32_bf16(af1, bf1, acc[1][1], 0,0,0); \
        acc[1][2] = __builtin_amdgcn_mfma_f32_16x16x32_bf16(af1, bf2, acc[1][2], 0,0,0); \
        acc[1][3] = __builtin_amdgcn_mfma_f32_16x16x32_bf16(af1, bf3, acc[1][3], 0,0,0); \
        acc[2][0] = __builtin_amdgcn_mfma_f32_16x16x32_bf16(af2, bf0, acc[2][0], 0,0,0); \
        acc[2][1] = __builtin_amdgcn_mfma_f32_16x16x32_bf16(af2, bf1, acc[2][1], 0,0,0); \
        acc[2][2] = __builtin_amdgcn_mfma_f32_16x16x32_bf16(af2, bf2, acc[2][2], 0,0,0); \
        acc[2][3] = __builtin_amdgcn_mfma_f32_16x16x32_bf16(af2, bf3, acc[2][3], 0,0,0); \
        acc[3][0] = __builtin_amdgcn_mfma_f32_16x16x32_bf16(af3, bf0, acc[3][0], 0,0,0); \
        acc[3][1] = __builtin_amdgcn_mfma_f32_16x16x32_bf16(af3, bf1, acc[3][1], 0,0,0); \
        acc[3][2] = __builtin_amdgcn_mfma_f32_16x16x32_bf16(af3, bf2, acc[3][2], 0,0,0); \
        acc[3][3] = __builtin_amdgcn_mfma_f32_16x16x32_bf16(af3, bf3, acc[3][3], 0,0,0); \
    }

// One expert per block: blockIdx = tile*8 + e (expert<->XCD affinity).
// m97-style schedule: stage(next) -> compute(cur) -> __syncthreads per slice.
__global__ __launch_bounds__(NTHREADS, 2) void moe_expert(
    const float* __restrict__ coords, int npts,
    const float* __restrict__ W0, const float* __restrict__ b0,
    const unsigned short* __restrict__ W1p, const float* __restrict__ b1,
    const unsigned short* __restrict__ W2p, const float* __restrict__ b2,
    const float* __restrict__ W3, const float* __restrict__ b3,
    float* __restrict__ ws)
{
    __shared__ __align__(16) unsigned short Act[NT * HD];      // 32 KB
    __shared__ __align__(16) unsigned short WbA[SLICE_ELEMS];  // 20 KB
    __shared__ __align__(16) unsigned short WbB[SLICE_ELEMS];  // 20 KB
    __shared__ float cbuf[NT * 3];
    __shared__ float pscr[NT * 4];

    const int t = threadIdx.x;
    const int lane = t & 63;
    const int w = t >> 6;       // 0..3: neuron group of 64
    const int l15 = lane & 15;
    const int kg = lane >> 4;
    const int e = blockIdx.x & 7;
    const int p0 = (blockIdx.x >> 3) * NT;

    const unsigned short* W1e = W1p + e * 8 * SLICE_ELEMS;
    const unsigned short* W2e = W2p + e * 8 * SLICE_ELEMS;

    if (t < NT * 3) {
        int idx = p0 * 3 + t;
        int lim = npts * 3 - 1;
        cbuf[t] = coords[idx < lim ? idx : lim];
    }
    const int j2 = (t & 127) * 2;
    const int prow0 = (t >> 7) * 32;
    const float wx0 = W0[(e*3+0)*HD + j2], wx1 = W0[(e*3+0)*HD + j2+1];
    const float wy0 = W0[(e*3+1)*HD + j2], wy1 = W0[(e*3+1)*HD + j2+1];
    const float wz0 = W0[(e*3+2)*HD + j2], wz1 = W0[(e*3+2)*HD + j2+1];
    const float bb0 = b0[e*HD + j2],       bb1 = b0[e*HD + j2+1];
    f32x4 b1v[4];
    #pragma unroll
    for (int mt = 0; mt < 4; ++mt)
        b1v[mt] = *(const f32x4*)(b1 + e*HD + w*64 + mt*16 + kg*4);
    __syncthreads();                    // cbuf visible

    // ---- kick off layer-1 slice 0 staging; hidden under L0 compute ----
    stage_slice(W1e, WbA, w, lane);

    // ---- layer 0: 3 -> 256, fp32 VALU, packed writes into Act ----
    #pragma unroll 4
    for (int pp = 0; pp < 32; ++pp) {
        int p = prow0 + pp;
        float x = cbuf[p*3], y = cbuf[p*3+1], z = cbuf[p*3+2];
        float h0 = fmaxf(x*wx0 + y*wy0 + z*wz0 + bb0, 0.f);
        float h1 = fmaxf(x*wx1 + y*wy1 + z*wz1 + bb1, 0.f);
        *(unsigned int*)(Act + swz(p, j2)) = pack2bf(h0, h1);
    }
    __syncthreads();                    // Act ready + slice-0 staging drained

    f32x4 acc[4][4];
    #pragma unroll
    for (int mt = 0; mt < 4; ++mt)
        #pragma unroll
        for (int nt = 0; nt < 4; ++nt)
            acc[mt][nt] = (f32x4){0.f, 0.f, 0.f, 0.f};

    // ---- layer 1: 8 K-slices, double-buffered; one __syncthreads per slice ----
    #pragma unroll
    for (int s = 0; s < 8; ++s) {
        unsigned short* cur = (s & 1) ? WbB : WbA;
        unsigned short* nxt = (s & 1) ? WbA : WbB;
        if (s < 7) stage_slice(W1e + (s+1) * SLICE_ELEMS, nxt, w, lane);
        else       stage_slice(W2e, nxt, w, lane);          // chain layer-2 s0
        KSLICE_BODY(cur)
        __syncthreads();                // drains DMA (nxt ready) + read/write fence
    }

    // ---- layer-1 epilogue: bias+relu -> Act in place ----
    #pragma unroll
    for (int mt = 0; mt < 4; ++mt) {
        const int n0 = w*64 + mt*16 + kg*4;
        const f32x4 bb = b1v[mt];
        #pragma unroll
        for (int nt = 0; nt < 4; ++nt) {
            const int p = nt*16 + l15;
            unsigned int lo = pack2bf(fmaxf(acc[mt][nt][0] + bb[0], 0.f),
                                      fmaxf(acc[mt][nt][1] + bb[1], 0.f));
            unsigned int hi = pack2bf(fmaxf(acc[mt][nt][2] + bb[2], 0.f),
                                      fmaxf(acc[mt][nt][3] + bb[3], 0.f));
            *(uint2*)(Act + swz(p, n0)) = make_uint2(lo, hi);
        }
    }
    __syncthreads();                    // Act W->R boundary

    #pragma unroll
    for (int mt = 0; mt < 4; ++mt)
        #pragma unroll
        for (int nt = 0; nt < 4; ++nt)
            acc[mt][nt] = (f32x4){0.f, 0.f, 0.f, 0.f};

    // ---- layer 2: 8 K-slices (s0 already staged into WbA) ----
    #pragma unroll
    for (int s = 0; s < 8; ++s) {
        unsigned short* cur = (s & 1) ? WbB : WbA;
        unsigned short* nxt = (s & 1) ? WbA : WbB;
        if (s < 7) stage_slice(W2e + (s+1) * SLICE_ELEMS, nxt, w, lane);
        KSLICE_BODY(cur)
        if (s < 7) __syncthreads();     // last slice needs no barrier
    }

    // ---- fused layer-2 epilogue + layer 3 (fp32, in registers) ----
    #pragma unroll
    for (int nt = 0; nt < 4; ++nt) {
        float s = 0.f;
        #pragma unroll
        for (int mt = 0; mt < 4; ++mt) {
            const int nb = w*64 + mt*16 + kg*4;
            const f32x4 bb = *(const f32x4*)(b2 + e*HD + nb);
            const f32x4 w3 = *(const f32x4*)(W3 + e*HD + nb);
            #pragma unroll
            for (int r = 0; r < 4; ++r)
                s += fmaxf(acc[mt][nt][r] + bb[r], 0.f) * w3[r];
        }
        s += __shfl_xor(s, 16);   // reduce over kg (4 lanes per point)
        s += __shfl_xor(s, 32);
        if (kg == 0) pscr[(nt*16 + l15) * 4 + w] = s;
    }
    __syncthreads();                    // pscr W->R boundary
    if (t < NT) {
        f32x4 v = *(const f32x4*)(pscr + t * 4);
        int p = p0 + t;
        if (p < npts) ws[e * npts + p] = v[0] + v[1] + v[2] + v[3] + b3[e];
    }
}

// Max over the 8 experts' partials.
__global__ void moe_reduce(const float* __restrict__ ws, float* __restrict__ out, int npts) {
    int p = blockIdx.x * 256 + threadIdx.x;
    if (p >= npts) return;
    float m = ws[p];
    #pragma unroll
    for (int e = 1; e < NE; ++e) m = fmaxf(m, ws[e * npts + p]);
    out[p] = m;
}

extern "C" void kernel_launch(void* const* d_in, const int* in_sizes, int n_in,
                              void* d_out, int out_size, void* d_ws, size_t ws_size,
                              hipStream_t stream) {
    const float* coords = (const float*)d_in[0];
    const float* W0 = (const float*)d_in[1];
    const float* b0 = (const float*)d_in[2];
    const float* W1 = (const float*)d_in[3];
    const float* b1 = (const float*)d_in[4];
    const float* W2 = (const float*)d_in[5];
    const float* b2 = (const float*)d_in[6];
    const float* W3 = (const float*)d_in[7];
    const float* b3 = (const float*)d_in[8];
    const int npts = in_sizes[0] / 3;

    unsigned short* W1p = (unsigned short*)d_ws;                   // 1.31 MB
    unsigned short* W2p = W1p + NE * 8 * SLICE_ELEMS;              // 1.31 MB
    float* eout = (float*)(W2p + NE * 8 * SLICE_ELEMS);            // 3.2 MB

    const int PREP_TOT = NE * 8 * SLICE_ELEMS;
    prep_weights<<<(PREP_TOT + 255) / 256, 256, 0, stream>>>(W1, W2, W1p, W2p);

    int ntiles = (npts + NT - 1) / NT;
    moe_expert<<<ntiles * NE, NTHREADS, 0, stream>>>(
        coords, npts, W0, b0, W1p, b1, W2p, b2, W3, b3, eout);

    moe_reduce<<<(npts + 255) / 256, 256, 0, stream>>>(eout, (float*)d_out, npts);
}